// Round 6
// baseline (69.339 us; speedup 1.0000x reference)
//
#include <hip/hip_runtime.h>

// CCM: causal 3x3 complex multi-frame filter.
// out[b,f,t,:] = sum_{i,j} (Hr+i*Hi)[b,i,j,t,f] * x[b, f+j-1, t+i-2, :]
// Hr = a0 - 0.5*(a1+a2); Hi = (sqrt(3)/2)*(a1-a2); a_k = m[b, 9k+3i+j, t, f]
//
// Flat e-mapping: thread tx owns elements e = 4tx..4tx+3 of the (t,f) tile
// plane -> all 27 m loads are aligned float4 (16 B/lane, m13 copy pattern),
// software-pipelined 3 groups deep. x window in LDS (XOR-swizzled). Output
// transposed through LDS so stores are 32 B/lane aligned dwordx4.

constexpr int B = 8, C = 27, T = 1000, F = 257;
constexpr int TCH = 4;                 // t per tile (mult of 4 -> aligned m)
constexpr int NT  = T / TCH;           // 250 -> 2000 blocks
constexpr int BLK = 320;               // 5 waves
constexpr int NA  = 257;               // active compute lanes
constexpr int TROW = TCH + 2;          // staged t rows: t0-2 .. t0+3
constexpr int FP   = 260;              // x-plane row pitch (dwords)
constexpr int PLSZ = TROW * FP + 32;   // plane size + swizzle pad
constexpr int LDSW = 2 * PLSZ;         // 3184 dwords (>= 2056 for res reuse)
constexpr size_t CS = (size_t)T * F;   // m channel stride (floats)

__device__ __forceinline__ int XSW(int a) { return a ^ (((a >> 5) & 7) << 2); }
__device__ __forceinline__ float comp(const float4& v, int r) {
    return r == 0 ? v.x : (r == 1 ? v.y : (r == 2 ? v.z : v.w));
}

__global__ __launch_bounds__(BLK, 4)
void ccm_kernel(const float* __restrict__ m,
                const float* __restrict__ x,
                float* __restrict__ out) {
    __shared__ float xs[LDSW];         // x planes, later reused for out tile

    const int bid = blockIdx.x;
    const int tc  = bid % NT;
    const int b   = bid / NT;
    const int t0  = tc * TCH;
    const int tx  = threadIdx.x;

    const float* xb = x + (size_t)b * F * T * 2;

    // ---- stage x window: lane = fp (f+1), 6 t-values = 3 aligned float4 ----
    if (tx < 259) {
        const int f = tx - 1;                      // -1..257
        float vre[6], vim[6];
        #pragma unroll
        for (int tt = 0; tt < 6; ++tt) { vre[tt] = 0.f; vim[tt] = 0.f; }
        if (f >= 0 && f < F) {
            if (t0 >= 2) {                         // 3 aligned float4 loads
                const float4* src = reinterpret_cast<const float4*>(
                    xb + ((size_t)f * T + (t0 - 2)) * 2);
                const float4 p0 = src[0], p1 = src[1], p2 = src[2];
                vre[0] = p0.x; vim[0] = p0.y; vre[1] = p0.z; vim[1] = p0.w;
                vre[2] = p1.x; vim[2] = p1.y; vre[3] = p1.z; vim[3] = p1.w;
                vre[4] = p2.x; vim[4] = p2.y; vre[5] = p2.z; vim[5] = p2.w;
            } else {                               // first tile: zero-fill t<0
                #pragma unroll
                for (int tt = 0; tt < 6; ++tt) {
                    const int t = t0 - 2 + tt;
                    if (t >= 0) {
                        const float2 v2 = *reinterpret_cast<const float2*>(
                            xb + ((size_t)f * T + t) * 2);
                        vre[tt] = v2.x; vim[tt] = v2.y;
                    }
                }
            }
        }
        #pragma unroll
        for (int tt = 0; tt < 6; ++tt) {
            const int a = XSW(tt * FP + tx);
            xs[a]        = vre[tt];
            xs[PLSZ + a] = vim[tt];
        }
    }

    // ---- decode: e = 4tx..4tx+3 ; e = tl*257 + f ----
    const int e0 = 4 * tx;
    const int tl = e0 / 257;                       // 0..3
    const int f0 = e0 - tl * 257;                  // 0..256
    const bool active = (tx < NA);

    const float SQ3_2 = 0.8660254037844386f;
    const float* mseg = m + (size_t)b * C * CS + (size_t)t0 * F + 4 * tx;

    float4 ga[3], gb[3], gc[3];
    float accr[4] = {0.f, 0.f, 0.f, 0.f};
    float acci[4] = {0.f, 0.f, 0.f, 0.f};

#define LOADG(Gv, n)                                                          \
    {                                                                         \
        Gv[0] = *reinterpret_cast<const float4*>(mseg + (size_t)(n) * CS);        \
        Gv[1] = *reinterpret_cast<const float4*>(mseg + (size_t)((n) + 9) * CS);  \
        Gv[2] = *reinterpret_cast<const float4*>(mseg + (size_t)((n) + 18) * CS); \
    }

#define MACG(Gv, n, WRE, WIE)                                                 \
    {                                                                         \
        constexpr int i_ = (n) / 3, j_ = (n) % 3;                             \
        _Pragma("unroll")                                                     \
        for (int r = 0; r < 4; ++r) {                                         \
            const float a0 = comp(Gv[0], r);                                  \
            const float a1 = comp(Gv[1], r);                                  \
            const float a2 = comp(Gv[2], r);                                  \
            const float hr = a0 - 0.5f * (a1 + a2);                           \
            const float hi = SQ3_2 * (a1 - a2);                               \
            accr[r] += hr * WRE(r, i_, j_) - hi * WIE(r, i_, j_);             \
            acci[r] += hr * WIE(r, i_, j_) + hi * WRE(r, i_, j_);             \
        }                                                                     \
    }

#define SCHED(WRE, WIE)                                                       \
    LOADG(ga, 0) LOADG(gb, 1) LOADG(gc, 2)                                    \
    MACG(ga, 0, WRE, WIE) LOADG(ga, 3)                                        \
    MACG(gb, 1, WRE, WIE) LOADG(gb, 4)                                        \
    MACG(gc, 2, WRE, WIE) LOADG(gc, 5)                                        \
    MACG(ga, 3, WRE, WIE) LOADG(ga, 6)                                        \
    MACG(gb, 4, WRE, WIE) LOADG(gb, 7)                                        \
    MACG(gc, 5, WRE, WIE) LOADG(gc, 8)                                        \
    MACG(ga, 6, WRE, WIE) MACG(gb, 7, WRE, WIE) MACG(gc, 8, WRE, WIE)

    __syncthreads();                   // x window visible

    int tlr_[4], fr_[4];
    #pragma unroll
    for (int r = 0; r < 4; ++r) {
        const int w = (f0 + r) >= 257 ? 1 : 0;
        tlr_[r] = tl + w;
        fr_[r]  = f0 + r - 257 * w;
    }

    if (active) {
        if (f0 <= 253) {
            // fast path: all 4 positions at row tl; taps rows tl..tl+2,
            // cols f0..f0+5 (pos r uses cols r..r+2) -> registers once
            float wr[3][6], wi[3][6];
            #pragma unroll
            for (int i = 0; i < 3; ++i) {
                const int rowb = (tl + i) * FP + f0;
                #pragma unroll
                for (int k = 0; k < 6; ++k) {
                    const int a = XSW(rowb + k);
                    wr[i][k] = xs[a];
                    wi[i][k] = xs[PLSZ + a];
                }
            }
#define WF_R(r, i, j) wr[i][(r) + (j)]
#define WF_I(r, i, j) wi[i][(r) + (j)]
            SCHED(WF_R, WF_I)
#undef WF_R
#undef WF_I
        } else {
            // slow path (2 lanes/block): positions wrap the t boundary
#define WS_R(r, i, j) xs[XSW((tlr_[r] + (i)) * FP + fr_[r] + (j))]
#define WS_I(r, i, j) xs[PLSZ + XSW((tlr_[r] + (i)) * FP + fr_[r] + (j))]
            SCHED(WS_R, WS_I)
#undef WS_R
#undef WS_I
        }
    }
#undef SCHED
#undef LOADG
#undef MACG

    __syncthreads();                   // everyone done reading xs

    // ---- transpose results through LDS: res[f][tl] as float2 ----
    if (active) {
        float2* res = reinterpret_cast<float2*>(xs);
        #pragma unroll
        for (int r = 0; r < 4; ++r)
            res[fr_[r] * 4 + tlr_[r]] = make_float2(accr[r], acci[r]);
    }
    __syncthreads();

    // ---- coalesced-chunk stores: lane f writes 32 B contiguous ----
    if (tx < NA) {
        const int f = tx;
        const float4* res4 = reinterpret_cast<const float4*>(xs);
        const float4 q0 = res4[f * 2];
        const float4 q1 = res4[f * 2 + 1];
        float* op = out + ((size_t)(b * F + f) * T + t0) * 2;
        reinterpret_cast<float4*>(op)[0] = q0;
        reinterpret_cast<float4*>(op)[1] = q1;
    }
}

extern "C" void kernel_launch(void* const* d_in, const int* in_sizes, int n_in,
                              void* d_out, int out_size, void* d_ws, size_t ws_size,
                              hipStream_t stream) {
    const float* m = (const float*)d_in[0];
    const float* x = (const float*)d_in[1];
    // d_in[2] = v is a fixed compile-time constant per the reference.
    float* out = (float*)d_out;

    const int grid = B * NT;               // 2000 blocks
    ccm_kernel<<<grid, BLK, 0, stream>>>(m, x, out);
}